// Round 7
// baseline (627.154 us; speedup 1.0000x reference)
//
#include <hip/hip_runtime.h>
#include <hip/hip_bf16.h>

#define NN 8192
#define FIN 512
#define FOUT 256
#define SLICES 8
#define JLEN (NN / SLICES)      // 1024
#define NCHUNK (JLEN / 64)      // 16

typedef __attribute__((ext_vector_type(8))) short short8;
typedef __attribute__((ext_vector_type(4))) float float4v;
typedef __attribute__((ext_vector_type(16))) float float16v;

__device__ __forceinline__ short f2bf(float f) {
    union { float f; unsigned u; } v; v.f = f;
    unsigned r = (v.u + 0x7FFFu + ((v.u >> 16) & 1u)) >> 16;
    return (short)r;
}

// ---------------- Kernel 0: Wt[n][k] = bf16(W[k][n]), tiled transpose ----------------
__global__ __launch_bounds__(256) void wt_kernel(const float* __restrict__ W,
                                                 short* __restrict__ Wt) {
    __shared__ short tile[32][33];
    int tx = threadIdx.x & 31, ty = threadIdx.x >> 5;
    int k0 = blockIdx.x * 32, n0 = blockIdx.y * 32;
#pragma unroll
    for (int r = 0; r < 32; r += 8)
        tile[ty + r][tx] = f2bf(W[(size_t)(k0 + ty + r) * FOUT + n0 + tx]);
    __syncthreads();
#pragma unroll
    for (int r = 0; r < 32; r += 8)
        Wt[(size_t)(n0 + ty + r) * FIN + k0 + tx] = tile[tx][ty + r];
}

// ---------------- Kernel 1: h2 (fragment-ready) = bf16(x@W); fused f_src/f_dst ----------------
// wave = 16m x 64n tile -> exactly one j-chunk (16 nodes) x 2 feat-tiles (32 each).
// Epilogue: per-wave LDS transpose -> h2 in 32x32x16-B-fragment order:
//   h2[((jc*8 + tile)*64 + lane)*8 + q] = h[jc*16 + (lane>>5)*8 + q][tile*32 + (lane&31)]
__global__ __launch_bounds__(256) void h_kernel(const float* __restrict__ x,
                                                const short* __restrict__ Wt,
                                                const float* __restrict__ a,
                                                short* __restrict__ h2,
                                                float* __restrict__ f_src,
                                                float* __restrict__ f_dst) {
    __shared__ short hls[4][64 * 16];    // per-wave private [n-local(64)][m-local(16)]

    int wave = (blockIdx.x << 2) + (threadIdx.x >> 6);
    int lane = threadIdx.x & 63;
    int m0 = (wave & 511) << 4;          // j-chunk jc = m0>>4
    int n0 = (wave >> 9) << 6;           // feat tiles n0/32, n0/32+1
    int lr = lane & 15, lq = lane >> 4;
    int l31 = lane & 31, lq2 = lane >> 5;

    const float* xrow = x + (size_t)(m0 + lr) * FIN + lq * 8;
    const short* wbase = Wt + (size_t)(n0 + lr) * FIN + lq * 8;

    float4v acc[4] = {};
    for (int k0 = 0; k0 < FIN; k0 += 32) {
        float4v xa = *(const float4v*)(xrow + k0);
        float4v xb = *(const float4v*)(xrow + k0 + 4);
        short8 av;
        av[0] = f2bf(xa[0]); av[1] = f2bf(xa[1]); av[2] = f2bf(xa[2]); av[3] = f2bf(xa[3]);
        av[4] = f2bf(xb[0]); av[5] = f2bf(xb[1]); av[6] = f2bf(xb[2]); av[7] = f2bf(xb[3]);
#pragma unroll
        for (int ct = 0; ct < 4; ct++) {
            short8 bv = *(const short8*)(wbase + (size_t)ct * 16 * FIN + k0);
            acc[ct] = __builtin_amdgcn_mfma_f32_16x16x32_bf16(av, bv, acc[ct], 0, 0, 0);
        }
    }
    // C/D: col = lr (n-local = ct*16+lr), row = lq*4 + reg (m-local).
    float s_part[4] = {0.f, 0.f, 0.f, 0.f};
    float d_part[4] = {0.f, 0.f, 0.f, 0.f};
    short* my = &hls[threadIdx.x >> 6][0];
#pragma unroll
    for (int ct = 0; ct < 4; ct++) {
        int n = n0 + ct * 16 + lr;
        float al = a[n], ar = a[FOUT + n];
#pragma unroll
        for (int reg = 0; reg < 4; reg++) {
            float hv = acc[ct][reg];
            s_part[reg] = fmaf(hv, al, s_part[reg]);
            d_part[reg] = fmaf(hv, ar, d_part[reg]);
        }
        // pack m-pairs -> b32 LDS writes at [n-local][m-local]
#pragma unroll
        for (int rp = 0; rp < 2; rp++) {
            unsigned pk = (unsigned)(unsigned short)f2bf(acc[ct][2 * rp]) |
                          ((unsigned)(unsigned short)f2bf(acc[ct][2 * rp + 1]) << 16);
            *(unsigned*)(my + (ct * 16 + lr) * 16 + lq * 4 + rp * 2) = pk;
        }
    }
    // read back in consumer-fragment order, write coalesced (compiler orders LDS ops)
    __builtin_amdgcn_s_waitcnt(0);  // lgkmcnt(0): ensure LDS writes landed (same wave)
#pragma unroll
    for (int nt = 0; nt < 2; nt++) {
        short8 fr = *(const short8*)(my + (nt * 32 + l31) * 16 + lq2 * 8);
        size_t jc = (size_t)(m0 >> 4);
        *(short8*)(h2 + ((jc * 8 + (n0 >> 5) + nt) * 64 + lane) * 8) = fr;
    }

#pragma unroll
    for (int off = 1; off < 16; off <<= 1) {
#pragma unroll
        for (int reg = 0; reg < 4; reg++) {
            s_part[reg] += __shfl_xor(s_part[reg], off);
            d_part[reg] += __shfl_xor(d_part[reg], off);
        }
    }
    const float LOG2E = 1.4426950408889634f;
    if (lr == 0) {
#pragma unroll
        for (int reg = 0; reg < 4; reg++) {
            atomicAdd(&f_src[m0 + lq * 4 + reg], s_part[reg] * LOG2E);
            atomicAdd(&f_dst[m0 + lq * 4 + reg], d_part[reg] * LOG2E);
        }
    }
}

// ---------------- Kernel 2: fused pack + masked-softmax-numerator @ h ----------------
// Grid (128 rowgroups, 8 slices) = 1024 blocks = 4/CU. Block 256 thr = 4 waves.
// Phase A: stream block's adj slice (64 rows x 1024 j = 256 KB) coalesced ->
//          __ballot -> u64 masks in LDS. ONE barrier total.
// Phase B: BARRIER-FREE K-loop: masks from LDS, f_dst from L2, B-fragments as
//          coalesced 1KB wave loads from fragment-ready h2 (L2-resident, 4 MB).
// Wave = 32 rows x 128 feats = 4 acc tiles of 32x32x16 (64 acc VGPR).
__global__ __launch_bounds__(256, 4) void gat_kernel(const int* __restrict__ adj,
                                                     const short* __restrict__ h2,
                                                     const float* __restrict__ f_src,
                                                     const float* __restrict__ f_dst,
                                                     float* __restrict__ Opart,
                                                     float* __restrict__ lpart) {
    __shared__ unsigned long long msk[64 * 17];      // stride 17 (odd), 8.7 KB

    const int t = threadIdx.x;
    const int lane = t & 63;
    const int w = t >> 6;
    const int l31 = lane & 31, lq = lane >> 5;
    const int wr = w >> 1, wc = w & 1;               // rowgroup 0..1, featgroup 0..1
    const int i0 = blockIdx.x * 64;
    const int slice = blockIdx.y;
    const int jbase = slice * JLEN;

    // ---- phase A: pack this block's adj slice to LDS masks (wave w: rows w*16..+16) ----
    {
        const int* ab = adj + (size_t)(i0 + (w << 4)) * NN + jbase + lane;
#pragma unroll 16
        for (int u = 0; u < 256; ++u) {
            int row = u >> 4, c = u & 15;
            int v = ab[(size_t)row * NN + c * 64];
            unsigned long long m = __ballot(v != 0);
            if (lane == 0) msk[((w << 4) + row) * 17 + c] = m;
        }
    }
    __syncthreads();                                 // the only block-wide barrier

    const int r = i0 + wr * 32 + l31;
    const float fs = f_src[r];
    const float* fdL = f_dst + jbase + lq * 8;
    const int jc0 = jbase >> 4;                      // global j-chunk base (16-wide)

    float16v acc[4] = {};
    float lp = 0.f;

    for (int c = 0; c < NCHUNK; ++c) {
        const unsigned long long bm = msk[(wr * 32 + l31) * 17 + c];
        const unsigned bmlo = (unsigned)bm, bmhi = (unsigned)(bm >> 32);
#pragma unroll
        for (int kk = 0; kk < 4; ++kk) {
            const int jo = c * 64 + kk * 16;
            float4 f0 = *(const float4*)(fdL + jo);
            float4 f1 = *(const float4*)(fdL + jo + 4);
            unsigned w32 = (kk < 2) ? bmlo : bmhi;
            unsigned m8 = (w32 >> ((kk & 1) * 16 + lq * 8)) & 0xffu;

            short8 af;
            const float* ff0 = (const float*)&f0;
            const float* ff1 = (const float*)&f1;
#pragma unroll
            for (int q = 0; q < 8; ++q) {
                float fdv = (q < 4) ? ff0[q] : ff1[q - 4];
                float y = fs + fdv;
                y = fmaxf(y, 0.2f * y);              // leaky_relu (log2-scaled domain)
                float e = exp2f(y);
                float p = (m8 & (1u << q)) ? e : 0.f;
                lp += p;
                af[q] = f2bf(p);
            }
            // B-fragments: coalesced 1KB wave loads from fragment-ready h2
            const size_t fb = ((size_t)(jc0 + c * 4 + kk) * 8 + wc * 4) * 512 + lane * 8;
            short8 b0 = *(const short8*)(h2 + fb);
            short8 b1 = *(const short8*)(h2 + fb + 512);
            short8 b2 = *(const short8*)(h2 + fb + 1024);
            short8 b3 = *(const short8*)(h2 + fb + 1536);
            acc[0] = __builtin_amdgcn_mfma_f32_32x32x16_bf16(af, b0, acc[0], 0, 0, 0);
            acc[1] = __builtin_amdgcn_mfma_f32_32x32x16_bf16(af, b1, acc[1], 0, 0, 0);
            acc[2] = __builtin_amdgcn_mfma_f32_32x32x16_bf16(af, b2, acc[2], 0, 0, 0);
            acc[3] = __builtin_amdgcn_mfma_f32_32x32x16_bf16(af, b3, acc[3], 0, 0, 0);
        }
    }

    // ---- partial row-sum l (featgroup 0 only; identical in group 1) ----
    lp += __shfl_xor(lp, 32);
    if (wc == 0 && lq == 0) lpart[(size_t)slice * NN + r] = lp;

    // ---- partial O: C/D 32x32 mapping: col=l31, row=(reg&3)+8*(reg>>2)+4*lq ----
    float* ob = Opart + ((size_t)slice * NN + i0 + wr * 32) * FOUT + wc * 128;
#pragma unroll
    for (int nt = 0; nt < 4; nt++) {
        int n = nt * 32 + l31;
#pragma unroll
        for (int reg = 0; reg < 16; reg++) {
            int row = (reg & 3) + 8 * (reg >> 2) + 4 * lq;
            ob[(size_t)row * FOUT + n] = acc[nt][reg];
        }
    }
}

// ---------------- Kernel 3: combine partials: out = sum_s O_s / sum_s l_s ----------------
__global__ __launch_bounds__(256) void combine_kernel(const float* __restrict__ Opart,
                                                      const float* __restrict__ lpart,
                                                      float* __restrict__ out) {
    int i = blockIdx.x, n = threadIdx.x;
    float o = 0.f, l = 0.f;
#pragma unroll
    for (int s = 0; s < SLICES; s++) {
        o += Opart[((size_t)s * NN + i) * FOUT + n];
        l += lpart[(size_t)s * NN + i];
    }
    out[(size_t)i * FOUT + n] = o / l;
}

extern "C" void kernel_launch(void* const* d_in, const int* in_sizes, int n_in,
                              void* d_out, int out_size, void* d_ws, size_t ws_size,
                              hipStream_t stream) {
    const float* x   = (const float*)d_in[0];
    const int*   adj = (const int*)d_in[1];
    const float* W   = (const float*)d_in[2];
    const float* a   = (const float*)d_in[3];
    float* out = (float*)d_out;

    char* ws = (char*)d_ws;
    short* h2    = (short*)ws;                                   // 4 MB (fragment-ready)
    short* Wt    = (short*)(ws + (4u << 20));                    // 256 KB
    float* f_src = (float*)(ws + (4u << 20) + (256u << 10));     // 32 KB
    float* f_dst = (float*)(ws + (4u << 20) + (288u << 10));     // 32 KB (contiguous after f_src)
    float* lpart = (float*)(ws + (4u << 20) + (320u << 10));     // 256 KB
    float* Opart = (float*)(ws + (16u << 20));                   // 64 MB (8 slices)

    hipMemsetAsync(f_src, 0, 2 * NN * sizeof(float), stream);
    wt_kernel<<<dim3(FIN / 32, FOUT / 32), 256, 0, stream>>>(W, Wt);
    h_kernel<<<512, 256, 0, stream>>>(x, Wt, a, h2, f_src, f_dst);
    gat_kernel<<<dim3(NN / 64, SLICES), 256, 0, stream>>>(adj, h2, f_src, f_dst,
                                                          Opart, lpart);
    combine_kernel<<<NN, 256, 0, stream>>>(Opart, lpart, out);
}